// Round 5
// baseline (70.200 us; speedup 1.0000x reference)
//
#include <hip/hip_runtime.h>

// Patch gather: out[n, r, c] = images[(p0[n] + r) * W + p1[n] + c]
// Fixed geometry: H = W = 4096, width = 128, N = 4096.
//
// 1) order_kernel (1 block, 256 thr): counting sort of patches by 16-row
//    band (p0 >> 4, 256 buckets). Parallel Hillis-Steele scan (no serial
//    section). Emits packed int4 records {n, p0, p1, 0} so the gather kernel
//    needs a single 16B load per block.
// 2) patch_gather_kernel: one block per patch in band-sorted order with
//    chunked XCD swizzle. All patches touching an image line run within a
//    ~2.6 MB window -> line fetched from HBM once (L2/L3 resident after).
//    Output uses non-temporal dwordx4 stores (268 MB stream, no reuse).

#define IMG_W   4096
#define PATCH_W 128
#define F4_PER_PATCH (PATCH_W * PATCH_W / 4)   // 4096
#define BLOCK   256
#define NB      256   // row-band buckets (p0 >> 4, p0 < 4096)

typedef float f32x4 __attribute__((ext_vector_type(4)));

__global__ __launch_bounds__(256) void order_kernel(
    const int* __restrict__ positions, int4* __restrict__ rec, int N)
{
    __shared__ int hist[NB];
    __shared__ int bufA[NB];
    __shared__ int bufB[NB];
    const int tid = threadIdx.x;

    hist[tid] = 0;
    __syncthreads();

    for (int i = tid; i < N; i += 256) {
        const int2 p = ((const int2*)positions)[i];
        atomicAdd(&hist[p.x >> 4], 1);
    }
    __syncthreads();

    // Hillis-Steele inclusive scan over NB=256 with 256 threads.
    bufA[tid] = hist[tid];
    __syncthreads();
    int* src = bufA;
    int* dst = bufB;
    for (int off = 1; off < NB; off <<= 1) {
        dst[tid] = src[tid] + (tid >= off ? src[tid - off] : 0);
        __syncthreads();
        int* t = src; src = dst; dst = t;
    }
    // exclusive base = inclusive - own count; reuse hist as cursor array
    const int base = src[tid] - hist[tid];
    __syncthreads();
    hist[tid] = base;
    __syncthreads();

    for (int i = tid; i < N; i += 256) {
        const int2 p = ((const int2*)positions)[i];
        const int slot = atomicAdd(&hist[p.x >> 4], 1);
        rec[slot] = make_int4(i, p.x, p.y, 0);
    }
}

__global__ __launch_bounds__(BLOCK) void patch_gather_kernel(
    const float* __restrict__ images,
    const int*   __restrict__ positions,
    const int4*  __restrict__ rec,       // may be null -> identity order
    float*       __restrict__ out,
    int N)
{
    int slot = blockIdx.x;
    if ((N & 7) == 0) {
        // chunked XCD swizzle: same-(blockIdx&7) blocks share an XCD; give
        // each XCD a contiguous chunk of the band-sorted patch list.
        const int nper = N >> 3;
        slot = (blockIdx.x & 7) * nper + (blockIdx.x >> 3);
    }

    int n, p0, p1;
    if (rec) {
        const int4 r4 = rec[slot];
        n = r4.x; p0 = r4.y; p1 = r4.z;
    } else {
        n = slot;
        p0 = positions[2 * n];
        p1 = positions[2 * n + 1];
    }

    const float* srcp = images + (size_t)p0 * IMG_W + p1;
    float*       dst  = out + (size_t)n * (PATCH_W * PATCH_W);

    #pragma unroll
    for (int it = 0; it < F4_PER_PATCH / BLOCK; ++it) {
        const int i  = it * BLOCK + threadIdx.x;   // float4 index within patch
        const int r  = i >> 5;                     // i / 32 (32 float4 per row)
        const int c  = (i & 31) << 2;              // (i % 32) * 4

        const float* s = srcp + (size_t)r * IMG_W + c;
        f32x4 v;
        v.x = s[0];
        v.y = s[1];
        v.z = s[2];
        v.w = s[3];
        __builtin_nontemporal_store(v, reinterpret_cast<f32x4*>(dst + (size_t)r * PATCH_W + c));
    }
}

extern "C" void kernel_launch(void* const* d_in, const int* in_sizes, int n_in,
                              void* d_out, int out_size, void* d_ws, size_t ws_size,
                              hipStream_t stream) {
    const float* images    = (const float*)d_in[0];
    const int*   positions = (const int*)d_in[1];
    float* out = (float*)d_out;

    const int N = in_sizes[1] / 2;   // 4096 patches

    int4* rec = nullptr;
    if (ws_size >= (size_t)N * sizeof(int4)) {
        rec = (int4*)d_ws;
        order_kernel<<<1, 256, 0, stream>>>(positions, rec, N);
    }
    patch_gather_kernel<<<N, BLOCK, 0, stream>>>(images, positions, rec, out, N);
}

// Round 6
// 65.596 us; speedup vs baseline: 1.0702x; 1.0702x over previous
//
#include <hip/hip_runtime.h>

// Patch gather: out[n, r, c] = images[(p0[n] + r) * W + p1[n] + c]
// Fixed geometry: H = W = 4096, width = 128, N = 4096.
//
// R4 base (66.1 us) + ONE change: cap occupancy at 3 blocks/CU via 48 KB of
// dummy dynamic LDS. Rationale: with ~8 blocks/CU resident, ~2048 patches are
// in flight, so the L3 reuse window is ~2048 x (64KB rd + 64KB wr-alloc)
// = 256 MB = L3 size -> thrash. Capping to 3 blocks/CU shrinks the window to
// ~96 MB so image lines survive between their first and last toucher.
// Streaming BW needs little occupancy (memsets hit 7 TB/s at 10% occ).
//
//  1) order_kernel: single-block counting sort by 32-row band (p0>>5, 128
//     buckets) into d_ws (R4 version, serial scan).
//  2) patch_gather_kernel: one block per patch in band-sorted order, chunked
//     XCD swizzle, nt dwordx4 stores.

#define IMG_W   4096
#define PATCH_W 128
#define F4_PER_PATCH (PATCH_W * PATCH_W / 4)   // 4096
#define BLOCK   256
#define NB      128   // row-band buckets (p0 >> 5, p0 < 4096)
#define OCC_LDS 49152 // 48 KB dummy dynamic LDS -> floor(160/48)=3 blocks/CU

typedef float f32x4 __attribute__((ext_vector_type(4)));

__global__ __launch_bounds__(1024) void order_kernel(
    const int* __restrict__ positions, int* __restrict__ order, int N)
{
    __shared__ int hist[NB];
    __shared__ int base[NB];
    const int tid = threadIdx.x;

    for (int b = tid; b < NB; b += blockDim.x) hist[b] = 0;
    __syncthreads();

    for (int i = tid; i < N; i += blockDim.x)
        atomicAdd(&hist[positions[2 * i] >> 5], 1);
    __syncthreads();

    if (tid == 0) {
        int s = 0;
        for (int b = 0; b < NB; ++b) { base[b] = s; s += hist[b]; }
    }
    __syncthreads();

    for (int b = tid; b < NB; b += blockDim.x) hist[b] = base[b];
    __syncthreads();

    for (int i = tid; i < N; i += blockDim.x) {
        const int slot = atomicAdd(&hist[positions[2 * i] >> 5], 1);
        order[slot] = i;
    }
}

__global__ __launch_bounds__(BLOCK) void patch_gather_kernel(
    const float* __restrict__ images,
    const int*   __restrict__ positions,
    const int*   __restrict__ order,     // may be null -> identity order
    float*       __restrict__ out,
    int N)
{
    int slot = blockIdx.x;
    if ((N & 7) == 0) {
        // chunked XCD swizzle: same-(blockIdx&7) blocks share an XCD; give
        // each XCD a contiguous chunk of the band-sorted patch list.
        const int nper = N >> 3;
        slot = (blockIdx.x & 7) * nper + (blockIdx.x >> 3);
    }
    const int n  = order ? order[slot] : slot;
    const int p0 = positions[2 * n];
    const int p1 = positions[2 * n + 1];

    const float* srcp = images + (size_t)p0 * IMG_W + p1;
    float*       dst  = out + (size_t)n * (PATCH_W * PATCH_W);

    #pragma unroll
    for (int it = 0; it < F4_PER_PATCH / BLOCK; ++it) {
        const int i  = it * BLOCK + threadIdx.x;   // float4 index within patch
        const int r  = i >> 5;                     // i / 32 (32 float4 per row)
        const int c  = (i & 31) << 2;              // (i % 32) * 4

        const float* s = srcp + (size_t)r * IMG_W + c;
        f32x4 v;
        v.x = s[0];
        v.y = s[1];
        v.z = s[2];
        v.w = s[3];
        __builtin_nontemporal_store(v, reinterpret_cast<f32x4*>(dst + (size_t)r * PATCH_W + c));
    }
}

extern "C" void kernel_launch(void* const* d_in, const int* in_sizes, int n_in,
                              void* d_out, int out_size, void* d_ws, size_t ws_size,
                              hipStream_t stream) {
    const float* images    = (const float*)d_in[0];
    const int*   positions = (const int*)d_in[1];
    float* out = (float*)d_out;

    const int N = in_sizes[1] / 2;   // 4096 patches

    int* order = nullptr;
    if (ws_size >= (size_t)N * sizeof(int)) {
        order = (int*)d_ws;
        order_kernel<<<1, 1024, 0, stream>>>(positions, order, N);
    }
    // 48 KB dummy dynamic LDS caps occupancy at 3 blocks/CU (see header).
    patch_gather_kernel<<<N, BLOCK, OCC_LDS, stream>>>(images, positions, order, out, N);
}